// Round 19
// baseline (182.093 us; speedup 1.0000x reference)
//
#include <hip/hip_runtime.h>
#include <hip/hip_bf16.h>
#include <math.h>

#define BATCH 4
#define CDIM 256
#define NDIM 4096
#define CLD 32
#define EPSBN 1e-5f
#define SPLITS 8
#define KEYS_PER_WAVE (NDIM / SPLITS)   // 512
#define LOG2E 1.4426950408889634f
#define NT (NDIM / 32)                  // 128 key-tiles per batch
#define NBLOCKS 512u

typedef unsigned short u16;
typedef unsigned int u32;
typedef __attribute__((ext_vector_type(8))) short bf16x8;   // 8 bf16 = 4 VGPR MFMA operand
typedef __attribute__((ext_vector_type(16))) float f32x16;  // 32x32 MFMA accumulator
typedef __attribute__((ext_vector_type(4))) u32 u32x4;
typedef __attribute__((ext_vector_type(2))) u32 u32x2;

__device__ inline u16 f2bf(float x) {
    return __builtin_bit_cast(u16, __float2bfloat16(x));
}
__device__ inline u32 pack_bf16x2(float a, float b) {
    return (u32)f2bf(a) | ((u32)f2bf(b) << 16);
}
// Truncation pack (P>0 hot path only): 3 ops, folds to v_perm_b32.
__device__ inline u32 pack_bf16x2_trunc(float a, float b) {
    u32 ua = __builtin_bit_cast(u32, a), ub = __builtin_bit_cast(u32, b);
    return (ua >> 16) | (ub & 0xFFFF0000u);
}
__device__ inline bf16x8 pack8(float4 a, float4 b) {
    u32x4 u;
    u.x = pack_bf16x2(a.x, a.y); u.y = pack_bf16x2(a.z, a.w);
    u.z = pack_bf16x2(b.x, b.y); u.w = pack_bf16x2(b.z, b.w);
    return __builtin_bit_cast(bf16x8, u);
}

// Device-scope grid barrier. Valid because grid (512 blocks) == exact resident
// capacity at __launch_bounds__(512,4): 4 waves/SIMD -> 2 blocks/CU x 256 CU.
// Counter zeroed via hipMemsetAsync before every launch (deterministic).
// Fuel-bounded spin: failure degrades to wrong answer, never a hang.
__device__ inline void gridbar(u32* ctr) {
    __threadfence();                      // release phase-1 writes device-wide
    __syncthreads();                      // whole block arrived
    if (threadIdx.x == 0) {
        atomicAdd(ctr, 1u);               // device-scope
        int fuel = 100000000;
        while (__hip_atomic_load(ctr, __ATOMIC_ACQUIRE, __HIP_MEMORY_SCOPE_AGENT) < NBLOCKS
               && --fuel) {
            __builtin_amdgcn_s_sleep(8);
        }
    }
    __syncthreads();                      // block proceeds together
}

// ---------------- Fused kernel: QKV projection -> grid barrier -> attention + out ----------------
__global__ __launch_bounds__(512, 4) void fused_all(
    const float* __restrict__ x,
    const float* __restrict__ w1, const float* __restrict__ w2, const float* __restrict__ w3,
    const float* __restrict__ b1s, const float* __restrict__ b1b, const float* __restrict__ b1m, const float* __restrict__ b1v,
    const float* __restrict__ b2s, const float* __restrict__ b2b, const float* __restrict__ b2m, const float* __restrict__ b2v,
    const float* __restrict__ b3s, const float* __restrict__ b3b, const float* __restrict__ b3m, const float* __restrict__ b3v,
    u16* __restrict__ qo, u16* __restrict__ ko, u16* __restrict__ vo,
    const float* __restrict__ wo,
    const float* __restrict__ b4s, const float* __restrict__ b4b,
    const float* __restrict__ b4m, const float* __restrict__ b4v,
    const float* __restrict__ gamma,
    float* __restrict__ out, u32* __restrict__ bar)
{
    // phase-1 LDS
    __shared__ float part[3][32][33];     // split-K partials, 3 pairs/block
    __shared__ float2 sbnp[3][32];        // per-pair BN (inv,bias)
    // phase-2 LDS
    __shared__ float o_lds[SPLITS][32][32];
    __shared__ float l_lds[SPLITS][32];
    __shared__ u16  p_lds[32][40];
    __shared__ float2 sbn4[CDIM];

    const int tid  = threadIdx.x;
    const int lane = tid & 63;
    const int col  = lane & 31;
    const int hi   = lane >> 5;
    const int w    = tid >> 6;            // wave 0..7
    const int blk  = blockIdx.x;          // 0..511

    // ================= phase 1: QKV projection (waves 0-5) =================
    const bool active = (w < 6);
    int b1_ = 0, mat = 0, tl = 0, kh = 0, pj = 0;
    f32x16 acc = {0.f,0.f,0.f,0.f, 0.f,0.f,0.f,0.f, 0.f,0.f,0.f,0.f, 0.f,0.f,0.f,0.f};
    if (active) {
        int t = blk * 6 + w;              // task 0..3071
        b1_ = t / 768;
        int r = t % 768;
        mat = r / 256;
        int r2 = r % 256;
        tl = r2 >> 1;
        kh = r2 & 1;
        pj = w >> 1;                      // pair 0..2

        if (kh == 0 && lane < 32 && hi == 0) {
            const float* ps = (mat == 0) ? b1s : (mat == 1) ? b2s : b3s;
            const float* pb = (mat == 0) ? b1b : (mat == 1) ? b2b : b3b;
            const float* pm = (mat == 0) ? b1m : (mat == 1) ? b2m : b3m;
            const float* pv = (mat == 0) ? b1v : (mat == 1) ? b2v : b3v;
            float inv  = ps[lane] / sqrtf(pv[lane] + EPSBN);
            float bias = pb[lane] - pm[lane] * inv;
            if (mat == 0) { inv *= LOG2E; bias *= LOG2E; }
            sbnp[pj][lane] = make_float2(inv, bias);
        }

        const int n0 = tl * 32;
        const float* wb = ((mat == 0) ? w1 : (mat == 1) ? w2 : w3)
                        + (size_t)col * CDIM + kh * 128 + 8 * hi;
        bf16x8 wf[8];
#pragma unroll
        for (int f = 0; f < 8; ++f) {
            float4 a = *reinterpret_cast<const float4*>(wb + 16 * f);
            float4 c = *reinterpret_cast<const float4*>(wb + 16 * f + 4);
            wf[f] = pack8(a, c);
        }

        const float* xb = x + (size_t)b1_ * CDIM * NDIM + n0 + col;
#pragma unroll
        for (int f = 0; f < 8; ++f) {
            float xv[8];
#pragma unroll
            for (int i = 0; i < 8; ++i)
                xv[i] = xb[(size_t)(kh * 128 + 16 * f + 8 * hi + i) * NDIM];
            u32x4 u;
            u.x = pack_bf16x2(xv[0], xv[1]); u.y = pack_bf16x2(xv[2], xv[3]);
            u.z = pack_bf16x2(xv[4], xv[5]); u.w = pack_bf16x2(xv[6], xv[7]);
            acc = __builtin_amdgcn_mfma_f32_32x32x16_bf16(wf[f], __builtin_bit_cast(bf16x8, u), acc, 0, 0, 0);
        }

        if (kh == 1) {
#pragma unroll
            for (int r = 0; r < 16; ++r) {
                int d = (r & 3) + 8 * (r >> 2) + 4 * hi;
                part[pj][d][col] = acc[r];
            }
        }
    } else {
        // idle waves 6-7: prefill phase-2 BN4 table (256 entries, 128 threads)
        int i = tid - 384;
#pragma unroll
        for (int j = 0; j < 2; ++j) {
            int o = i + 128 * j;
            float inv = b4s[o] / sqrtf(b4v[o] + EPSBN);
            sbn4[o] = make_float2(inv, b4b[o] - b4m[o] * inv);
        }
    }
    __syncthreads();
    if (active && kh == 0) {
#pragma unroll
        for (int r = 0; r < 16; ++r) {
            int d = (r & 3) + 8 * (r >> 2) + 4 * hi;
            acc[r] += part[pj][d][col];
        }
        const int n0 = tl * 32;
        if (mat < 2) {
            u16* dst = ((mat == 0) ? qo : ko) + ((size_t)b1_ * NDIM + n0 + col) * CLD;
#pragma unroll
            for (int g2 = 0; g2 < 4; ++g2) {
                float y[4];
#pragma unroll
                for (int j = 0; j < 4; ++j) {
                    int o = 8 * g2 + 4 * hi + j;
                    float2 ib = sbnp[pj][o];
                    y[j] = fmaxf(fmaf(acc[4 * g2 + j], ib.x, ib.y), 0.f);
                }
                u32x2 s;
                s.x = pack_bf16x2(y[0], y[1]); s.y = pack_bf16x2(y[2], y[3]);
                *reinterpret_cast<u32x2*>(dst + 8 * g2 + 4 * hi) = s;
            }
        } else {
            int p = col;
            int q2 = (p >> 2) & 3;
            if (q2 == 1 || q2 == 2) p ^= 12;
            u16* base = vo + (size_t)(b1_ * NT + tl) * 1024 + p;
#pragma unroll
            for (int r = 0; r < 16; ++r) {
                int d = (r & 3) + 8 * (r >> 2) + 4 * hi;
                float2 ib = sbnp[pj][d];
                base[d * 32] = f2bf(fmaxf(fmaf(acc[r], ib.x, ib.y), 0.f));
            }
        }
    }

    // ================= grid barrier =================
    gridbar(bar);

    // ================= phase 2: attention + output projection (r17 verbatim) =================
    const int b    = blk >> 7;
    const int q0   = (blk & 127) * 32;

    const u16* qp = qo + ((size_t)b * NDIM + q0 + col) * CLD + 8 * hi;
    bf16x8 qf0 = *reinterpret_cast<const bf16x8*>(qp);
    bf16x8 qf1 = *reinterpret_cast<const bf16x8*>(qp + 16);

    f32x16 o = {0.f,0.f,0.f,0.f, 0.f,0.f,0.f,0.f, 0.f,0.f,0.f,0.f, 0.f,0.f,0.f,0.f};
    float l_lane = 0.f;

    const int kstart = w * KEYS_PER_WAVE;
    const u16* kb = ko + (size_t)b * NDIM * CLD;
    const u16* vb = vo + (size_t)(b * NT) * 1024 + (size_t)col * 32 + 8 * hi;

    for (int kt = 0; kt < KEYS_PER_WAVE; kt += 64) {
        const int k0 = kstart + kt;
        const u16* kp1 = kb + (size_t)(k0 + col) * CLD + 8 * hi;
        bf16x8 kf10 = *reinterpret_cast<const bf16x8*>(kp1);
        bf16x8 kf11 = *reinterpret_cast<const bf16x8*>(kp1 + 16);
        const u16* kp2 = kp1 + 32 * CLD;
        bf16x8 kf20 = *reinterpret_cast<const bf16x8*>(kp2);
        bf16x8 kf21 = *reinterpret_cast<const bf16x8*>(kp2 + 16);

        const u16* vp = vb + (size_t)(k0 >> 5) * 1024;
        bf16x8 vf10 = *reinterpret_cast<const bf16x8*>(vp);
        bf16x8 vf11 = *reinterpret_cast<const bf16x8*>(vp + 16);
        bf16x8 vf20 = *reinterpret_cast<const bf16x8*>(vp + 1024);
        bf16x8 vf21 = *reinterpret_cast<const bf16x8*>(vp + 1040);

        f32x16 sa = {0.f,0.f,0.f,0.f, 0.f,0.f,0.f,0.f, 0.f,0.f,0.f,0.f, 0.f,0.f,0.f,0.f};
        f32x16 sb = {0.f,0.f,0.f,0.f, 0.f,0.f,0.f,0.f, 0.f,0.f,0.f,0.f, 0.f,0.f,0.f,0.f};
        sa = __builtin_amdgcn_mfma_f32_32x32x16_bf16(kf10, qf0, sa, 0, 0, 0);
        sa = __builtin_amdgcn_mfma_f32_32x32x16_bf16(kf11, qf1, sa, 0, 0, 0);
        sb = __builtin_amdgcn_mfma_f32_32x32x16_bf16(kf20, qf0, sb, 0, 0, 0);
        sb = __builtin_amdgcn_mfma_f32_32x32x16_bf16(kf21, qf1, sb, 0, 0, 0);

        float psum = 0.f;
#pragma unroll
        for (int r = 0; r < 16; ++r) { sa[r] = exp2f(sa[r]); psum += sa[r]; }
#pragma unroll
        for (int r = 0; r < 16; ++r) { sb[r] = exp2f(sb[r]); psum += sb[r]; }
        l_lane += psum;

        u32x4 p10, p11, p20, p21;
        p10.x = pack_bf16x2_trunc(sa[0],  sa[1]);  p10.y = pack_bf16x2_trunc(sa[2],  sa[3]);
        p10.z = pack_bf16x2_trunc(sa[4],  sa[5]);  p10.w = pack_bf16x2_trunc(sa[6],  sa[7]);
        p11.x = pack_bf16x2_trunc(sa[8],  sa[9]);  p11.y = pack_bf16x2_trunc(sa[10], sa[11]);
        p11.z = pack_bf16x2_trunc(sa[12], sa[13]); p11.w = pack_bf16x2_trunc(sa[14], sa[15]);
        p20.x = pack_bf16x2_trunc(sb[0],  sb[1]);  p20.y = pack_bf16x2_trunc(sb[2],  sb[3]);
        p20.z = pack_bf16x2_trunc(sb[4],  sb[5]);  p20.w = pack_bf16x2_trunc(sb[6],  sb[7]);
        p21.x = pack_bf16x2_trunc(sb[8],  sb[9]);  p21.y = pack_bf16x2_trunc(sb[10], sb[11]);
        p21.z = pack_bf16x2_trunc(sb[12], sb[13]); p21.w = pack_bf16x2_trunc(sb[14], sb[15]);

        o = __builtin_amdgcn_mfma_f32_32x32x16_bf16(vf10, __builtin_bit_cast(bf16x8, p10), o, 0, 0, 0);
        o = __builtin_amdgcn_mfma_f32_32x32x16_bf16(vf11, __builtin_bit_cast(bf16x8, p11), o, 0, 0, 0);
        o = __builtin_amdgcn_mfma_f32_32x32x16_bf16(vf20, __builtin_bit_cast(bf16x8, p20), o, 0, 0, 0);
        o = __builtin_amdgcn_mfma_f32_32x32x16_bf16(vf21, __builtin_bit_cast(bf16x8, p21), o, 0, 0, 0);
    }

#pragma unroll
    for (int r = 0; r < 16; ++r) {
        int d = (r & 3) + 8 * (r >> 2) + 4 * hi;
        o_lds[w][d][col] = o[r];
    }
    float l_tot = l_lane + __shfl_xor(l_lane, 32);
    if (hi == 0) l_lds[w][col] = l_tot;
    __syncthreads();

    {
        const int qq = tid & 31;
        const int dp = tid >> 5;
        float den = 0.f;
#pragma unroll
        for (int s = 0; s < SPLITS; ++s) den += l_lds[s][qq];
        float inv = 1.f / den;
        float a0 = 0.f, a1 = 0.f;
#pragma unroll
        for (int s = 0; s < SPLITS; ++s) {
            a0 += o_lds[s][2 * dp][qq];
            a1 += o_lds[s][2 * dp + 1][qq];
        }
        *reinterpret_cast<u32*>(&p_lds[qq][2 * dp]) = pack_bf16x2(a0 * inv, a1 * inv);
    }
    __syncthreads();

    const int o0 = w * 32;
    const float* wp = wo + (size_t)(o0 + col) * CLD + 8 * hi;
    bf16x8 wf0 = pack8(*reinterpret_cast<const float4*>(wp),
                       *reinterpret_cast<const float4*>(wp + 4));
    bf16x8 wf1 = pack8(*reinterpret_cast<const float4*>(wp + 16),
                       *reinterpret_cast<const float4*>(wp + 20));
    bf16x8 pf0 = *reinterpret_cast<const bf16x8*>(&p_lds[col][8 * hi]);
    bf16x8 pf1 = *reinterpret_cast<const bf16x8*>(&p_lds[col][16 + 8 * hi]);

    f32x16 acc2 = {0.f,0.f,0.f,0.f, 0.f,0.f,0.f,0.f, 0.f,0.f,0.f,0.f, 0.f,0.f,0.f,0.f};
    acc2 = __builtin_amdgcn_mfma_f32_32x32x16_bf16(wf0, pf0, acc2, 0, 0, 0);
    acc2 = __builtin_amdgcn_mfma_f32_32x32x16_bf16(wf1, pf1, acc2, 0, 0, 0);

    const float gm = gamma[0];
#pragma unroll
    for (int r = 0; r < 16; ++r) {
        int orow = (r & 3) + 8 * (r >> 2) + 4 * hi;
        float2 ib = sbn4[o0 + orow];
        o_lds[w][orow][col] = gm * fmaxf(fmaf(acc2[r], ib.x, ib.y), 0.f);
    }
    __syncthreads();

    {
        const int c4 = (lane & 7) * 4;
#pragma unroll
        for (int pass = 0; pass < 4; ++pass) {
            int row = pass * 8 + (lane >> 3);
            size_t idx = ((size_t)b * CDIM + o0 + row) * NDIM + q0 + c4;
            float4 yv = *reinterpret_cast<const float4*>(&o_lds[w][row][c4]);
            float4 xv = *reinterpret_cast<const float4*>(x + idx);
            float4 rr;
            rr.x = yv.x + xv.x; rr.y = yv.y + xv.y;
            rr.z = yv.z + xv.z; rr.w = yv.w + xv.w;
            *reinterpret_cast<float4*>(out + idx) = rr;
        }
    }
}

extern "C" void kernel_launch(void* const* d_in, const int* in_sizes, int n_in,
                              void* d_out, int out_size, void* d_ws, size_t ws_size,
                              hipStream_t stream) {
    const float* x   = (const float*)d_in[0];
    const float* w1  = (const float*)d_in[1];
    const float* w2  = (const float*)d_in[2];
    const float* w3  = (const float*)d_in[3];
    const float* wo  = (const float*)d_in[4];
    const float* b1s = (const float*)d_in[5];
    const float* b1b = (const float*)d_in[6];
    const float* b1m = (const float*)d_in[7];
    const float* b1v = (const float*)d_in[8];
    const float* b2s = (const float*)d_in[9];
    const float* b2b = (const float*)d_in[10];
    const float* b2m = (const float*)d_in[11];
    const float* b2v = (const float*)d_in[12];
    const float* b3s = (const float*)d_in[13];
    const float* b3b = (const float*)d_in[14];
    const float* b3m = (const float*)d_in[15];
    const float* b3v = (const float*)d_in[16];
    const float* b4s = (const float*)d_in[17];
    const float* b4b = (const float*)d_in[18];
    const float* b4m = (const float*)d_in[19];
    const float* b4v = (const float*)d_in[20];
    const float* gm  = (const float*)d_in[21];
    float* out = (float*)d_out;

    // ws layout (bytes):
    //   [0, 1MB)   : qbf bf16 [B][N][32]  (pre-scaled by log2e)
    //   [1MB, 2MB) : kbf bf16 [B][N][32]
    //   [2MB, 3MB) : vbf bf16 [B][NT][32d][32slot]  (kappa slot order)
    //   [3MB, +64) : grid-barrier counter
    char* W = (char*)d_ws;
    u16* qbf = (u16*)W;
    u16* kbf = (u16*)(W + (1u << 20));
    u16* vbf = (u16*)(W + (2u << 20));
    u32* bar = (u32*)(W + (3u << 20));

    hipMemsetAsync(bar, 0, 64, stream);

    fused_all<<<dim3(NBLOCKS), 512, 0, stream>>>(
        x, w1, w2, w3,
        b1s, b1b, b1m, b1v,
        b2s, b2b, b2m, b2v,
        b3s, b3b, b3m, b3v,
        qbf, kbf, vbf,
        wo, b4s, b4b, b4m, b4v, gm, out, bar);
}

// Round 20
// 41.392 us; speedup vs baseline: 4.3992x; 4.3992x over previous
//
#include <hip/hip_runtime.h>
#include <hip/hip_bf16.h>
#include <math.h>

#define BATCH 4
#define CDIM 256
#define NDIM 4096
#define CLD 32
#define EPSBN 1e-5f
#define SPLITS 8
#define KEYS_PER_WAVE (NDIM / SPLITS)   // 512
#define LOG2E 1.4426950408889634f
#define NT (NDIM / 32)                  // 128 key-tiles per batch

typedef unsigned short u16;
typedef unsigned int u32;
typedef __attribute__((ext_vector_type(8))) short bf16x8;   // 8 bf16 = 4 VGPR MFMA operand
typedef __attribute__((ext_vector_type(16))) float f32x16;  // 32x32 MFMA accumulator
typedef __attribute__((ext_vector_type(4))) u32 u32x4;
typedef __attribute__((ext_vector_type(2))) u32 u32x2;

__device__ inline u16 f2bf(float x) {
    return __builtin_bit_cast(u16, __float2bfloat16(x));
}
__device__ inline u32 pack_bf16x2(float a, float b) {
    return (u32)f2bf(a) | ((u32)f2bf(b) << 16);
}
// Truncation pack for POSITIVE values (P = 2^S > 0): 3 ops, folds to v_perm_b32.
// <=1 ulp error vs RNE's 1/2 ulp -- only used on the attention P fragments.
__device__ inline u32 pack_bf16x2_trunc(float a, float b) {
    u32 ua = __builtin_bit_cast(u32, a), ub = __builtin_bit_cast(u32, b);
    return (ua >> 16) | (ub & 0xFFFF0000u);
}
__device__ inline bf16x8 pack8(float4 a, float4 b) {
    u32x4 u;
    u.x = pack_bf16x2(a.x, a.y); u.y = pack_bf16x2(a.z, a.w);
    u.z = pack_bf16x2(b.x, b.y); u.w = pack_bf16x2(b.z, b.w);
    return __builtin_bit_cast(bf16x8, u);
}

// ---------------- Kernel 1: MFMA QKV projection + BN + ReLU -> bf16 ----------------
// Round-14 structure: split-K wave pairs, grid (64, 3, B), block 256 = 4 waves,
// 3072 waves = 3/SIMD. RNE packs (r18 showed trunc here is neutral; RNE keeps
// absmax margin). q (xLOG2E folded into BN), k -> [B][N][32] bf16;
// v -> tiled [B][NT][32d][32slot], slot = kappa(key&31)
// (kappa: p^=12 if ((p>>2)&3) in {1,2}).
__global__ __launch_bounds__(256) void proj_qkv(
    const float* __restrict__ x,
    const float* __restrict__ w1, const float* __restrict__ w2, const float* __restrict__ w3,
    const float* __restrict__ b1s, const float* __restrict__ b1b, const float* __restrict__ b1m, const float* __restrict__ b1v,
    const float* __restrict__ b2s, const float* __restrict__ b2b, const float* __restrict__ b2m, const float* __restrict__ b2v,
    const float* __restrict__ b3s, const float* __restrict__ b3b, const float* __restrict__ b3m, const float* __restrict__ b3v,
    u16* __restrict__ qo, u16* __restrict__ ko, u16* __restrict__ vo)
{
    __shared__ float2 sbn[32];           // (inv, bias) for this mat's 32 channels
    __shared__ float part[2][32][33];    // per-tile partial acc (padded)

    const int tid  = threadIdx.x;
    const int lane = tid & 63;
    const int col  = lane & 31;
    const int hi   = lane >> 5;
    const int wv   = tid >> 6;
    const int tloc = wv >> 1;            // tile within block: 0..1
    const int kh   = wv & 1;             // K-half: 0 -> c 0..127, 1 -> c 128..255
    const int mat  = blockIdx.y;         // 0:q/w1 1:k/w2 2:v/w3
    const int b    = blockIdx.z;
    const int tl   = blockIdx.x * 2 + tloc;  // n-tile within batch, 0..127
    const int n0   = tl * 32;

    if (tid < 32) {
        const float* ps = (mat == 0) ? b1s : (mat == 1) ? b2s : b3s;
        const float* pb = (mat == 0) ? b1b : (mat == 1) ? b2b : b3b;
        const float* pm = (mat == 0) ? b1m : (mat == 1) ? b2m : b3m;
        const float* pv = (mat == 0) ? b1v : (mat == 1) ? b2v : b3v;
        float inv  = ps[tid] / sqrtf(pv[tid] + EPSBN);
        float bias = pb[tid] - pm[tid] * inv;
        if (mat == 0) { inv *= LOG2E; bias *= LOG2E; }   // relu(y)*s == relu(y*s), s>0
        sbn[tid] = make_float2(inv, bias);
    }

    // A-frags: W_m[o=col][c], 8 frags of k=16 in this wave's K-half
    const float* wb = ((mat == 0) ? w1 : (mat == 1) ? w2 : w3)
                    + (size_t)col * CDIM + kh * 128 + 8 * hi;
    bf16x8 wf[8];
#pragma unroll
    for (int f = 0; f < 8; ++f) {
        float4 a = *reinterpret_cast<const float4*>(wb + 16 * f);
        float4 c = *reinterpret_cast<const float4*>(wb + 16 * f + 4);
        wf[f] = pack8(a, c);
    }

    const float* xb = x + (size_t)b * CDIM * NDIM + n0 + col;

    f32x16 acc = {0.f,0.f,0.f,0.f, 0.f,0.f,0.f,0.f, 0.f,0.f,0.f,0.f, 0.f,0.f,0.f,0.f};
#pragma unroll
    for (int f = 0; f < 8; ++f) {
        float xv[8];
#pragma unroll
        for (int i = 0; i < 8; ++i)
            xv[i] = xb[(size_t)(kh * 128 + 16 * f + 8 * hi + i) * NDIM];   // coalesced
        u32x4 u;
        u.x = pack_bf16x2(xv[0], xv[1]); u.y = pack_bf16x2(xv[2], xv[3]);
        u.z = pack_bf16x2(xv[4], xv[5]); u.w = pack_bf16x2(xv[6], xv[7]);
        acc = __builtin_amdgcn_mfma_f32_32x32x16_bf16(wf[f], __builtin_bit_cast(bf16x8, u), acc, 0, 0, 0);
    }

    // ---- pair-combine: kh=1 publishes, kh=0 sums + epilogue ----
    if (kh == 1) {
#pragma unroll
        for (int r = 0; r < 16; ++r) {
            int d = (r & 3) + 8 * (r >> 2) + 4 * hi;
            part[tloc][d][col] = acc[r];
        }
    }
    __syncthreads();
    if (kh == 1) return;

#pragma unroll
    for (int r = 0; r < 16; ++r) {
        int d = (r & 3) + 8 * (r >> 2) + 4 * hi;
        acc[r] += part[tloc][d][col];
    }

    if (mat < 2) {
        // [B][N][32]: lane owns n=n0+col; o chunks {0-3,8-11,16-19,24-27}+4hi
        u16* dst = ((mat == 0) ? qo : ko) + ((size_t)b * NDIM + n0 + col) * CLD;
#pragma unroll
        for (int g2 = 0; g2 < 4; ++g2) {
            float y[4];
#pragma unroll
            for (int j = 0; j < 4; ++j) {
                int o = 8 * g2 + 4 * hi + j;
                float2 ib = sbn[o];
                y[j] = fmaxf(fmaf(acc[4 * g2 + j], ib.x, ib.y), 0.f);
            }
            u32x2 s;
            s.x = pack_bf16x2(y[0], y[1]); s.y = pack_bf16x2(y[2], y[3]);
            *reinterpret_cast<u32x2*>(dst + 8 * g2 + 4 * hi) = s;
        }
    } else {
        // tiled V: [B][NT][32d][32slot], slot = kappa(col), rows = d
        int p = col;
        int q2 = (p >> 2) & 3;
        if (q2 == 1 || q2 == 2) p ^= 12;
        u16* base = vo + (size_t)(b * NT + tl) * 1024 + p;
#pragma unroll
        for (int r = 0; r < 16; ++r) {
            int d = (r & 3) + 8 * (r >> 2) + 4 * hi;
            float2 ib = sbn[d];
            base[d * 32] = f2bf(fmaxf(fmaf(acc[r], ib.x, ib.y), 0.f));
        }
    }
}

// ---------------- Kernel 2: fused attention + output projection ----------------
// Round-17 (best measured): grid (N/32, B), block 512 = 8 waves (4/SIMD).
// No-max unnormalized softmax (post-ReLU Q,K => S>=0, bounded << 127 in log2
// domain so 2^S cannot overflow f32). P packed by TRUNCATION (confirmed -2us).
// LDS split-combine -> bf16 p_lds -> per-wave 2-MFMA output projection ->
// BN4+ReLU+gamma in accumulator layout -> LDS transpose -> float4 epilogue.
__global__ __launch_bounds__(512, 4) void attn_fused(
    const u16* __restrict__ q, const u16* __restrict__ k, const u16* __restrict__ v,
    const float* __restrict__ wo,
    const float* __restrict__ b4s, const float* __restrict__ b4b,
    const float* __restrict__ b4m, const float* __restrict__ b4v,
    const float* __restrict__ x, const float* __restrict__ gamma,
    float* __restrict__ out)
{
    __shared__ float o_lds[SPLITS][32][32];   // 32 KB; reused as y' tile store
    __shared__ float l_lds[SPLITS][32];
    __shared__ u16  p_lds[32][40];            // 80B rows: 16B-aligned, bank-spread
    __shared__ float2 sbn4[CDIM];             // (inv, bias) for all 256 outputs

    const int tid  = threadIdx.x;
    const int lane = tid & 63;
    const int w    = tid >> 6;            // split / o-tile 0..7
    const int b    = blockIdx.y;
    const int q0   = blockIdx.x * 32;
    const int col  = lane & 31;
    const int hi   = lane >> 5;

    if (tid < CDIM) {
        float inv = b4s[tid] / sqrtf(b4v[tid] + EPSBN);
        sbn4[tid] = make_float2(inv, b4b[tid] - b4m[tid] * inv);
    }

    const u16* qp = q + ((size_t)b * NDIM + q0 + col) * CLD + 8 * hi;
    bf16x8 qf0 = *reinterpret_cast<const bf16x8*>(qp);
    bf16x8 qf1 = *reinterpret_cast<const bf16x8*>(qp + 16);

    f32x16 o = {0.f,0.f,0.f,0.f, 0.f,0.f,0.f,0.f, 0.f,0.f,0.f,0.f, 0.f,0.f,0.f,0.f};
    float l_lane = 0.f;                   // per-lane partial (this half's 16 rows)

    const int kstart = w * KEYS_PER_WAVE;
    const u16* kb = k + (size_t)b * NDIM * CLD;
    const u16* vb = v + (size_t)(b * NT) * 1024 + (size_t)col * 32 + 8 * hi;

    for (int kt = 0; kt < KEYS_PER_WAVE; kt += 64) {
        const int k0 = kstart + kt;
        const u16* kp1 = kb + (size_t)(k0 + col) * CLD + 8 * hi;
        bf16x8 kf10 = *reinterpret_cast<const bf16x8*>(kp1);
        bf16x8 kf11 = *reinterpret_cast<const bf16x8*>(kp1 + 16);
        const u16* kp2 = kp1 + 32 * CLD;
        bf16x8 kf20 = *reinterpret_cast<const bf16x8*>(kp2);
        bf16x8 kf21 = *reinterpret_cast<const bf16x8*>(kp2 + 16);

        const u16* vp = vb + (size_t)(k0 >> 5) * 1024;
        bf16x8 vf10 = *reinterpret_cast<const bf16x8*>(vp);
        bf16x8 vf11 = *reinterpret_cast<const bf16x8*>(vp + 16);
        bf16x8 vf20 = *reinterpret_cast<const bf16x8*>(vp + 1024);
        bf16x8 vf21 = *reinterpret_cast<const bf16x8*>(vp + 1040);

        f32x16 sa = {0.f,0.f,0.f,0.f, 0.f,0.f,0.f,0.f, 0.f,0.f,0.f,0.f, 0.f,0.f,0.f,0.f};
        f32x16 sb = {0.f,0.f,0.f,0.f, 0.f,0.f,0.f,0.f, 0.f,0.f,0.f,0.f, 0.f,0.f,0.f,0.f};
        sa = __builtin_amdgcn_mfma_f32_32x32x16_bf16(kf10, qf0, sa, 0, 0, 0);
        sa = __builtin_amdgcn_mfma_f32_32x32x16_bf16(kf11, qf1, sa, 0, 0, 0);
        sb = __builtin_amdgcn_mfma_f32_32x32x16_bf16(kf20, qf0, sb, 0, 0, 0);
        sb = __builtin_amdgcn_mfma_f32_32x32x16_bf16(kf21, qf1, sb, 0, 0, 0);

        // ---- unnormalized softmax: P = 2^S directly ----
        float psum = 0.f;
#pragma unroll
        for (int r = 0; r < 16; ++r) { sa[r] = exp2f(sa[r]); psum += sa[r]; }
#pragma unroll
        for (int r = 0; r < 16; ++r) { sb[r] = exp2f(sb[r]); psum += sb[r]; }
        l_lane += psum;

        // ---- P fragments direct from accumulator (trunc pack; V kappa-permuted) ----
        u32x4 p10, p11, p20, p21;
        p10.x = pack_bf16x2_trunc(sa[0],  sa[1]);  p10.y = pack_bf16x2_trunc(sa[2],  sa[3]);
        p10.z = pack_bf16x2_trunc(sa[4],  sa[5]);  p10.w = pack_bf16x2_trunc(sa[6],  sa[7]);
        p11.x = pack_bf16x2_trunc(sa[8],  sa[9]);  p11.y = pack_bf16x2_trunc(sa[10], sa[11]);
        p11.z = pack_bf16x2_trunc(sa[12], sa[13]); p11.w = pack_bf16x2_trunc(sa[14], sa[15]);
        p20.x = pack_bf16x2_trunc(sb[0],  sb[1]);  p20.y = pack_bf16x2_trunc(sb[2],  sb[3]);
        p20.z = pack_bf16x2_trunc(sb[4],  sb[5]);  p20.w = pack_bf16x2_trunc(sb[6],  sb[7]);
        p21.x = pack_bf16x2_trunc(sb[8],  sb[9]);  p21.y = pack_bf16x2_trunc(sb[10], sb[11]);
        p21.z = pack_bf16x2_trunc(sb[12], sb[13]); p21.w = pack_bf16x2_trunc(sb[14], sb[15]);

        o = __builtin_amdgcn_mfma_f32_32x32x16_bf16(vf10, __builtin_bit_cast(bf16x8, p10), o, 0, 0, 0);
        o = __builtin_amdgcn_mfma_f32_32x32x16_bf16(vf11, __builtin_bit_cast(bf16x8, p11), o, 0, 0, 0);
        o = __builtin_amdgcn_mfma_f32_32x32x16_bf16(vf20, __builtin_bit_cast(bf16x8, p20), o, 0, 0, 0);
        o = __builtin_amdgcn_mfma_f32_32x32x16_bf16(vf21, __builtin_bit_cast(bf16x8, p21), o, 0, 0, 0);
    }

    // ---- publish partials ----
#pragma unroll
    for (int r = 0; r < 16; ++r) {
        int d = (r & 3) + 8 * (r >> 2) + 4 * hi;
        o_lds[w][d][col] = o[r];
    }
    float l_tot = l_lane + __shfl_xor(l_lane, 32);
    if (hi == 0) l_lds[w][col] = l_tot;
    __syncthreads();

    // ---- combine 8 splits -> normalized agg tile in p_lds (bf16) ----
    {
        const int qq = tid & 31;
        const int dp = tid >> 5;          // d-pair 0..15
        float den = 0.f;
#pragma unroll
        for (int s = 0; s < SPLITS; ++s) den += l_lds[s][qq];
        float inv = 1.f / den;
        float a0 = 0.f, a1 = 0.f;
#pragma unroll
        for (int s = 0; s < SPLITS; ++s) {
            a0 += o_lds[s][2 * dp][qq];
            a1 += o_lds[s][2 * dp + 1][qq];
        }
        *reinterpret_cast<u32*>(&p_lds[qq][2 * dp]) = pack_bf16x2(a0 * inv, a1 * inv);
    }
    __syncthreads();

    // ---- output projection: wave w -> o-tile o0 = w*32, 2 MFMA ----
    const int o0 = w * 32;
    const float* wp = wo + (size_t)(o0 + col) * CLD + 8 * hi;
    bf16x8 wf0 = pack8(*reinterpret_cast<const float4*>(wp),
                       *reinterpret_cast<const float4*>(wp + 4));
    bf16x8 wf1 = pack8(*reinterpret_cast<const float4*>(wp + 16),
                       *reinterpret_cast<const float4*>(wp + 20));
    bf16x8 pf0 = *reinterpret_cast<const bf16x8*>(&p_lds[col][8 * hi]);
    bf16x8 pf1 = *reinterpret_cast<const bf16x8*>(&p_lds[col][16 + 8 * hi]);

    f32x16 acc = {0.f,0.f,0.f,0.f, 0.f,0.f,0.f,0.f, 0.f,0.f,0.f,0.f, 0.f,0.f,0.f,0.f};
    acc = __builtin_amdgcn_mfma_f32_32x32x16_bf16(wf0, pf0, acc, 0, 0, 0);
    acc = __builtin_amdgcn_mfma_f32_32x32x16_bf16(wf1, pf1, acc, 0, 0, 0);

    // BN4 + ReLU + gamma in accumulator layout -> y' into freed o_lds[w]
    const float gm = gamma[0];
#pragma unroll
    for (int r = 0; r < 16; ++r) {
        int orow = (r & 3) + 8 * (r >> 2) + 4 * hi;
        float2 ib = sbn4[o0 + orow];
        o_lds[w][orow][col] = gm * fmaxf(fmaf(acc[r], ib.x, ib.y), 0.f);
    }
    __syncthreads();

    // vectorized residual + store: lane -> rows pass*8+(lane>>3), cols (lane&7)*4
    {
        const int c4 = (lane & 7) * 4;
#pragma unroll
        for (int pass = 0; pass < 4; ++pass) {
            int row = pass * 8 + (lane >> 3);
            size_t idx = ((size_t)b * CDIM + o0 + row) * NDIM + q0 + c4;
            float4 yv = *reinterpret_cast<const float4*>(&o_lds[w][row][c4]);
            float4 xv = *reinterpret_cast<const float4*>(x + idx);
            float4 rr;
            rr.x = yv.x + xv.x; rr.y = yv.y + xv.y;
            rr.z = yv.z + xv.z; rr.w = yv.w + xv.w;
            *reinterpret_cast<float4*>(out + idx) = rr;
        }
    }
}

extern "C" void kernel_launch(void* const* d_in, const int* in_sizes, int n_in,
                              void* d_out, int out_size, void* d_ws, size_t ws_size,
                              hipStream_t stream) {
    const float* x   = (const float*)d_in[0];
    const float* w1  = (const float*)d_in[1];
    const float* w2  = (const float*)d_in[2];
    const float* w3  = (const float*)d_in[3];
    const float* wo  = (const float*)d_in[4];
    const float* b1s = (const float*)d_in[5];
    const float* b1b = (const float*)d_in[6];
    const float* b1m = (const float*)d_in[7];
    const float* b1v = (const float*)d_in[8];
    const float* b2s = (const float*)d_in[9];
    const float* b2b = (const float*)d_in[10];
    const float* b2m = (const float*)d_in[11];
    const float* b2v = (const float*)d_in[12];
    const float* b3s = (const float*)d_in[13];
    const float* b3b = (const float*)d_in[14];
    const float* b3m = (const float*)d_in[15];
    const float* b3v = (const float*)d_in[16];
    const float* b4s = (const float*)d_in[17];
    const float* b4b = (const float*)d_in[18];
    const float* b4m = (const float*)d_in[19];
    const float* b4v = (const float*)d_in[20];
    const float* gm  = (const float*)d_in[21];
    float* out = (float*)d_out;

    // ws layout (bytes):
    //   [0, 1MB)   : qbf bf16 [B][N][32]  (pre-scaled by log2e)
    //   [1MB, 2MB) : kbf bf16 [B][N][32]
    //   [2MB, 3MB) : vbf bf16 [B][NT][32d][32slot]  (kappa slot order)
    char* W = (char*)d_ws;
    u16* qbf = (u16*)W;
    u16* kbf = (u16*)(W + (1u << 20));
    u16* vbf = (u16*)(W + (2u << 20));

    dim3 gp(64, 3, BATCH);
    proj_qkv<<<gp, 256, 0, stream>>>(x, w1, w2, w3,
                                     b1s, b1b, b1m, b1v,
                                     b2s, b2b, b2m, b2v,
                                     b3s, b3b, b3m, b3v,
                                     qbf, kbf, vbf);

    dim3 ga(NDIM / 32, BATCH);
    attn_fused<<<ga, 512, 0, stream>>>(qbf, kbf, vbf, wo, b4s, b4b, b4m, b4v,
                                       x, gm, out);
}